// Round 2
// baseline (533.272 us; speedup 1.0000x reference)
//
#include <hip/hip_runtime.h>
#include <cstdint>
#include <cstddef>

// out[n, r*256+c] = sum_{e,i} x[n, cell(r,e)*64+i] * v[e,i,r,c] + b[r*256+c]
// 49 independent (8192x192)@(192x256) GEMMs. bf16 MFMA, fp32 accumulate.
// R4: (a) x_prepass deleted -- GEMM reads fp32 x directly from L2/L3 and
// casts in-register (A is cache-served; the prepass was 85 MB of pure HBM
// overhead). (b) out stores are nontemporal (write-once stream was evicting
// the wt/x read hotset from the 4 MB per-XCD L2). (c) XCD-chunked bid swizzle
// (T1): each XCD owns 8 contiguous m-panels x all 49 r -> x panel L2-fill
// per XCD drops 28 MB -> 7 MB. GEMM itself: zero LDS, zero barriers,
// register-double-buffered fragments, fully unrolled K-loop (R3 structure).

#define XCOLS   1728      // 27*64
#define ROWS_W  49
#define KTOT    192       // 3*64
#define OUTW    12544     // 49*256

typedef __attribute__((ext_vector_type(8))) short short8;
typedef __attribute__((ext_vector_type(4))) float f32x4;

struct CellTab { int c[ROWS_W][3]; };

// Faithful constexpr port of init_wincon_matrix(): cells[r][e] = board cell of
// the e-th put() for column r (step cycles 0,1,2 within each column).
constexpr CellTab make_cells() {
    CellTab t{};
    int step = 0, col = 0;
    int x = 0, y = 0, z = 0;
#define PUT() do { t.c[col][step] = x + 3*y + 9*z; step = (step + 1) % 3; } while (0)
    for (x = 0; x < 3; ++x) {
        for (y = 0; y < 3; ++y) {
            for (z = 0; z < 3; ++z) PUT();
            ++col;
        }
        for (z = 0; z < 3; ++z) {
            for (y = 0; y < 3; ++y) PUT();
            ++col;
        }
        for (y = 0; y < 3; ++y) { z = y; PUT(); }
        ++col;
        for (y = 0; y < 3; ++y) { z = 2 - y; PUT(); }
        ++col;
    }
    for (z = 0; z < 3; ++z) {
        for (y = 0; y < 3; ++y) {
            for (x = 0; x < 3; ++x) PUT();
            ++col;
        }
        for (y = 0; y < 3; ++y) { x = y; PUT(); }
        ++col;
        for (y = 0; y < 3; ++y) { x = 2 - y; PUT(); }
        ++col;
    }
    for (y = 0; y < 3; ++y) {
        for (z = 0; z < 3; ++z) { x = z; PUT(); }
        ++col;
        for (z = 0; z < 3; ++z) { x = 2 - z; PUT(); }
        ++col;
    }
    for (x = 0; x < 3; ++x) { y = x; z = x; PUT(); }
    ++col;
    for (x = 0; x < 3; ++x) { y = 2 - x; z = 2 - x; PUT(); }
    ++col;
    for (x = 0; x < 3; ++x) { y = x; z = 2 - x; PUT(); }
    ++col;
    for (x = 0; x < 3; ++x) { z = x; y = 2 - x; PUT(); }
    ++col;
#undef PUT
    return t;
}

__constant__ CellTab CELLS = make_cells();

__device__ __forceinline__ unsigned short f2bf(float f) {
    union { float f; unsigned u; } a; a.f = f;
    unsigned u = a.u;
    return (unsigned short)((u + 0x7fffu + ((u >> 16) & 1u)) >> 16);  // RNE
}

// ---------------------------------------------------------------------------
// Prepass: wt2[r][kc][q][c][j] (bf16) = v[k][r][c], k = kc*32 + q*8 + j.
// This is exactly the per-lane B-fragment layout of the GEMM: a wave's B-frag
// load for (kc, nt) is 4 x 256B fully-contiguous segments.
// Reads of v are coalesced (1 KB per (q,j) across the 256 threads).
// ---------------------------------------------------------------------------
__global__ __launch_bounds__(256) void wt_prepass(const float* __restrict__ v,
                                                  unsigned short* __restrict__ wt) {
    const int kc = blockIdx.x;   // 0..5
    const int r  = blockIdx.y;   // 0..48
    const int c  = threadIdx.x;  // 0..255
#pragma unroll
    for (int q = 0; q < 4; ++q) {
        short8 s;
#pragma unroll
        for (int j = 0; j < 8; ++j) {
            const int k = kc * 32 + q * 8 + j;
            s[j] = (short)f2bf(v[(size_t)k * OUTW + r * 256 + c]);
        }
        *(short8*)(wt + ((((size_t)r * 6 + kc) * 4 + q) * 256 + c) * 8) = s;
    }
}

// ---------------------------------------------------------------------------
// Main GEMM. Block = one (r, 128-row m-tile) x ALL 256 cols. 256 thr / 4 waves.
// Wave (wh = wave>>1, half = wave&1) owns rows [wh*64, +64) x cols
// [half*128, +128): acc = 4 mt x 8 nt x f32x4 = 128 VGPR.
// NO LDS, NO barriers: wt (4.8 MB) + x m-panels are L2/L3-resident, so each
// wave streams fragments directly from cache:
//   B-frag (kc,nt): wt2[r][kc][quad][half*128+nt*16+l15][0..7]  (k-contiguous,
//     per-instruction 4 x 256B coalesced segments)
//   A-frag (kc,mt): x fp32, 2 x float4 per lane, cast to bf16 in-register
//     (~8 VALU ops per frag -- A is cache-served, prepass was pure overhead)
// Double-buffered afr/bfr registers; fully unrolled kc-loop pipelines loads of
// kc+1 under the 32 MFMAs of kc. Epilogue stores are NONTEMPORAL (write-once
// stream must not evict the L2 read hotset). 2 blocks/CU.
// XCD-chunked swizzle: each XCD gets a contiguous 392-block chunk
// (8 m-panels x 49 r) -> x panel L2-fill per XCD 7 MB instead of 28 MB.
// ---------------------------------------------------------------------------
__global__ __launch_bounds__(256, 2) void tic_gemm(
    const float* __restrict__ x,
    const unsigned short* __restrict__ wt,
    const float* __restrict__ bias,
    float* __restrict__ out)
{
    // T1 chunked swizzle: 3136 blocks = 8 XCDs x 392. Bijective.
    const int swz = (blockIdx.x & 7) * 392 + (blockIdx.x >> 3);
    const int m     = swz / 49;
    const int r     = swz % 49;
    const int mbase = m * 128;

    const int t    = threadIdx.x;
    const int wave = t >> 6;
    const int lane = t & 63;
    const int l15  = lane & 15;
    const int quad = lane >> 4;
    const int half = wave & 1;   // column half (0: cols 0-127, 1: 128-255)
    const int wh   = wave >> 1;  // row half (0: rows 0-63, 1: 64-127)

    const int cells[3] = { CELLS.c[r][0], CELLS.c[r][1], CELLS.c[r][2] };

    // acc init = bias (per-column, identical for all rows)
    f32x4 acc[4][8];
#pragma unroll
    for (int nt = 0; nt < 8; ++nt) {
        const float bv = bias[r * 256 + half * 128 + nt * 16 + l15];
        f32x4 a; a[0] = bv; a[1] = bv; a[2] = bv; a[3] = bv;
#pragma unroll
        for (int mt = 0; mt < 4; ++mt) acc[mt][nt] = a;
    }

    // per-lane B base: wt2 element (((r*6+kc)*4+quad)*256 + half*128 + l15)*8
    // kc advances by 4*256*8 = 8192 elems; nt advances by 16*8 = 128 elems.
    const unsigned short* wbase =
        wt + ((size_t)(r * 24 + quad) * 256 + half * 128 + l15) * 8;

    short8 afr[2][4];  // [kc-parity][mt] -- A frags, cast from fp32 x
    short8 bfr[2][8];  // [kc-parity][nt] -- B frags straight from wt2

    auto loadA = [&](int kc, int p) {
        const int e = kc >> 1, h = kc & 1;
        const int colb = cells[e] * 64 + h * 32 + quad * 8;
#pragma unroll
        for (int mt = 0; mt < 4; ++mt) {
            const int row = mbase + wh * 64 + mt * 16 + l15;
            const float* src = x + (size_t)row * XCOLS + colb;
            const float4 a0 = *(const float4*)src;
            const float4 a1 = *(const float4*)(src + 4);
            short8 s;
            s[0] = (short)f2bf(a0.x); s[1] = (short)f2bf(a0.y);
            s[2] = (short)f2bf(a0.z); s[3] = (short)f2bf(a0.w);
            s[4] = (short)f2bf(a1.x); s[5] = (short)f2bf(a1.y);
            s[6] = (short)f2bf(a1.z); s[7] = (short)f2bf(a1.w);
            afr[p][mt] = s;
        }
    };
    auto loadB = [&](int kc, int p) {
        const unsigned short* src = wbase + (size_t)kc * 8192;
#pragma unroll
        for (int nt = 0; nt < 8; ++nt)
            bfr[p][nt] = *(const short8*)(src + nt * 128);
    };

    loadA(0, 0);
    loadB(0, 0);

#pragma unroll
    for (int kc = 0; kc < 6; ++kc) {
        const int p = kc & 1;
        if (kc < 5) {
            loadB(kc + 1, p ^ 1);
            loadA(kc + 1, p ^ 1);
        }
#pragma unroll
        for (int nt = 0; nt < 8; ++nt) {
#pragma unroll
            for (int mt = 0; mt < 4; ++mt)
                acc[mt][nt] = __builtin_amdgcn_mfma_f32_16x16x32_bf16(
                    afr[p][mt], bfr[p][nt], acc[mt][nt], 0, 0, 0);
        }
    }

    // Epilogue: C/D layout col=lane&15, row=quad*4+reg  [m89-verified]
    // Each 16-lane group writes one aligned 64-B line per (mt,v4,nt).
    // Nontemporal: out is write-once, keep it out of L2.
#pragma unroll
    for (int mt = 0; mt < 4; ++mt) {
#pragma unroll
        for (int v4 = 0; v4 < 4; ++v4) {
            const int row = mbase + wh * 64 + mt * 16 + quad * 4 + v4;
            float* orow = out + (size_t)row * OUTW + r * 256 + half * 128;
#pragma unroll
            for (int nt = 0; nt < 8; ++nt)
                __builtin_nontemporal_store(acc[mt][nt][v4], orow + nt * 16 + l15);
        }
    }
}

extern "C" void kernel_launch(void* const* d_in, const int* in_sizes, int n_in,
                              void* d_out, int out_size, void* d_ws, size_t ws_size,
                              hipStream_t stream) {
    const float* x  = (const float*)d_in[0];   // (8192, 1728) fp32
    const float* v  = (const float*)d_in[1];   // (3, 64, 49, 256) fp32
    const float* b  = (const float*)d_in[2];   // (12544,) fp32
    float* out = (float*)d_out;                // (8192, 12544) fp32

    unsigned short* wt = (unsigned short*)d_ws;          // 4.8 MB bf16 wt2

    wt_prepass<<<dim3(6, 49), dim3(256), 0, stream>>>(v, wt);
    tic_gemm<<<dim3(64 * 49), dim3(256), 0, stream>>>(x, wt, b, out);
}

// Round 3
// 529.598 us; speedup vs baseline: 1.0069x; 1.0069x over previous
//
#include <hip/hip_runtime.h>
#include <cstdint>
#include <cstddef>

// out[n, r*256+c] = sum_{e,i} x[n, cell(r,e)*64+i] * v[e,i,r,c] + b[r*256+c]
// 49 GEMMs sharing one A. R5: LOOP INVERSION -- one block per CU owns a
// 32-row x panel, stages it to LDS ONCE (bf16, XOR-swizzled), then loops all
// 49 r. A-side traffic drops 1.39 GB -> 57 MB (read-once); kernel becomes
// HBM-write-bound (~75 us floor). One barrier per block. out stores are
// nontemporal (write-once stream must not evict the shared wt slice from L2).

#define XCOLS   1728      // 27*64
#define ROWS_W  49
#define KTOT    192       // 3*64
#define OUTW    12544     // 49*256

typedef __attribute__((ext_vector_type(8))) short short8;
typedef __attribute__((ext_vector_type(4))) short short4v;
typedef __attribute__((ext_vector_type(4))) float f32x4;

struct CellTab { int c[ROWS_W][3]; };

// Faithful constexpr port of init_wincon_matrix(): cells[r][e] = board cell of
// the e-th put() for column r (step cycles 0,1,2 within each column).
constexpr CellTab make_cells() {
    CellTab t{};
    int step = 0, col = 0;
    int x = 0, y = 0, z = 0;
#define PUT() do { t.c[col][step] = x + 3*y + 9*z; step = (step + 1) % 3; } while (0)
    for (x = 0; x < 3; ++x) {
        for (y = 0; y < 3; ++y) {
            for (z = 0; z < 3; ++z) PUT();
            ++col;
        }
        for (z = 0; z < 3; ++z) {
            for (y = 0; y < 3; ++y) PUT();
            ++col;
        }
        for (y = 0; y < 3; ++y) { z = y; PUT(); }
        ++col;
        for (y = 0; y < 3; ++y) { z = 2 - y; PUT(); }
        ++col;
    }
    for (z = 0; z < 3; ++z) {
        for (y = 0; y < 3; ++y) {
            for (x = 0; x < 3; ++x) PUT();
            ++col;
        }
        for (y = 0; y < 3; ++y) { x = y; PUT(); }
        ++col;
        for (y = 0; y < 3; ++y) { x = 2 - y; PUT(); }
        ++col;
    }
    for (y = 0; y < 3; ++y) {
        for (z = 0; z < 3; ++z) { x = z; PUT(); }
        ++col;
        for (z = 0; z < 3; ++z) { x = 2 - z; PUT(); }
        ++col;
    }
    for (x = 0; x < 3; ++x) { y = x; z = x; PUT(); }
    ++col;
    for (x = 0; x < 3; ++x) { y = 2 - x; z = 2 - x; PUT(); }
    ++col;
    for (x = 0; x < 3; ++x) { y = x; z = 2 - x; PUT(); }
    ++col;
    for (x = 0; x < 3; ++x) { z = x; y = 2 - x; PUT(); }
    ++col;
#undef PUT
    return t;
}

__constant__ CellTab CELLS = make_cells();

__device__ __forceinline__ unsigned short f2bf(float f) {
    union { float f; unsigned u; } a; a.f = f;
    unsigned u = a.u;
    return (unsigned short)((u + 0x7fffu + ((u >> 16) & 1u)) >> 16);  // RNE
}

// ---------------------------------------------------------------------------
// Prepass: wt2[r][kc][q][c][j] (bf16) = v[k][r][c], k = kc*32 + q*8 + j.
// Exactly the per-lane B-fragment layout of the GEMM (256B-coalesced reads).
// ---------------------------------------------------------------------------
__global__ __launch_bounds__(256) void wt_prepass(const float* __restrict__ v,
                                                  unsigned short* __restrict__ wt) {
    const int kc = blockIdx.x;   // 0..5
    const int r  = blockIdx.y;   // 0..48
    const int c  = threadIdx.x;  // 0..255
#pragma unroll
    for (int q = 0; q < 4; ++q) {
        short8 s;
#pragma unroll
        for (int j = 0; j < 8; ++j) {
            const int k = kc * 32 + q * 8 + j;
            s[j] = (short)f2bf(v[(size_t)k * OUTW + r * 256 + c]);
        }
        *(short8*)(wt + ((((size_t)r * 6 + kc) * 4 + q) * 256 + c) * 8) = s;
    }
}

// ---------------------------------------------------------------------------
// Main GEMM, loop-inverted. Block = 32-row m-panel (grid 256 = 1/CU).
// Stage x[mbase..mbase+32) x 1728 as bf16 into LDS once (110.6 KB), swizzled:
//   16B chunk (row, c16) lives at chunk index row*216 + (c16 ^ (row&7))
//   (bijective within each cell's 8 chunks; kills the 32-way stride-3456B
//   bank conflict on A-frag reads -> ~2-way = free).
// Then for each r: 4 waves x (32 rows x 64 cols each), acc = 2mt x 4nt x f32x4
// (32 VGPR). B frags stream from wt2 (L2-hot: all 256 blocks walk the same r
// sequence). kc register-double-buffered. Epilogue: NT stores (write-once).
// ---------------------------------------------------------------------------
__global__ __launch_bounds__(256) void tic_gemm(
    const float* __restrict__ x,
    const unsigned short* __restrict__ wt,
    const float* __restrict__ bias,
    float* __restrict__ out)
{
    const int mbase = blockIdx.x * 32;
    const int t    = threadIdx.x;
    const int wave = t >> 6;
    const int lane = t & 63;
    const int l15  = lane & 15;
    const int quad = lane >> 4;

    __shared__ __align__(16) unsigned short Xs[32 * 216 * 8];  // 110.6 KB

    // ---- one-time staging: 32x1728 fp32 -> bf16 LDS, 54 float4 per thread
#pragma unroll 6
    for (int i = 0; i < 54; ++i) {
        const int flat = i * 256 + t;          // 0..13823 = 32 rows * 432 f4
        const int row  = flat / 432;
        const int c4   = flat - row * 432;
        const float4 a = *(const float4*)(x + (size_t)(mbase + row) * XCOLS + c4 * 4);
        const int c16 = c4 >> 1, hh = c4 & 1;
        const int sc  = c16 ^ (row & 7);
        short4v s;
        s[0] = (short)f2bf(a.x); s[1] = (short)f2bf(a.y);
        s[2] = (short)f2bf(a.z); s[3] = (short)f2bf(a.w);
        *(short4v*)&Xs[(row * 216 + sc) * 8 + hh * 4] = s;
    }
    __syncthreads();   // the ONLY barrier; Xs is read-only from here on

    f32x4  acc[2][4];
    short8 afr[2][2];  // [kc-parity][mt]
    short8 bfr[2][4];  // [kc-parity][nt]

#pragma unroll 1
    for (int r = 0; r < ROWS_W; ++r) {
        const int c0 = CELLS.c[r][0], c1 = CELLS.c[r][1], c2 = CELLS.c[r][2];
        const int cell[3] = { c0, c1, c2 };

        // acc init = bias (per-column, identical for all rows)
#pragma unroll
        for (int nt = 0; nt < 4; ++nt) {
            const float bv = bias[r * 256 + wave * 64 + nt * 16 + l15];
            f32x4 a; a[0] = bv; a[1] = bv; a[2] = bv; a[3] = bv;
            acc[0][nt] = a; acc[1][nt] = a;
        }

        auto loadA = [&](int kc, int p) {
            const int e = kc >> 1, h = kc & 1;
            const int cb = cell[e] * 8 + h * 4 + quad;   // 16B-chunk col index
#pragma unroll
            for (int mt = 0; mt < 2; ++mt) {
                const int row = mt * 16 + l15;           // row&7 == l15&7
                afr[p][mt] = *(const short8*)&Xs[(row * 216 + (cb ^ (l15 & 7))) * 8];
            }
        };
        auto loadB = [&](int kc, int p) {
            const unsigned short* src =
                wt + ((size_t)((r * 6 + kc) * 4 + quad) * 256 + wave * 64 + l15) * 8;
#pragma unroll
            for (int nt = 0; nt < 4; ++nt)
                bfr[p][nt] = *(const short8*)(src + nt * 128);
        };

        loadA(0, 0);
        loadB(0, 0);

#pragma unroll
        for (int kc = 0; kc < 6; ++kc) {
            const int p = kc & 1;
            if (kc < 5) {
                loadB(kc + 1, p ^ 1);
                loadA(kc + 1, p ^ 1);
            }
#pragma unroll
            for (int nt = 0; nt < 4; ++nt) {
#pragma unroll
                for (int mt = 0; mt < 2; ++mt)
                    acc[mt][nt] = __builtin_amdgcn_mfma_f32_16x16x32_bf16(
                        afr[p][mt], bfr[p][nt], acc[mt][nt], 0, 0, 0);
            }
        }

        // Epilogue: C/D layout col=lane&15, row=quad*4+reg  [m89-verified]
        // 64B line per 16-lane group; NT -> bypass L2 (write-once stream).
#pragma unroll
        for (int mt = 0; mt < 2; ++mt) {
#pragma unroll
            for (int v4 = 0; v4 < 4; ++v4) {
                const int row = mbase + mt * 16 + quad * 4 + v4;
                float* orow = out + (size_t)row * OUTW + r * 256 + wave * 64;
#pragma unroll
                for (int nt = 0; nt < 4; ++nt)
                    __builtin_nontemporal_store(acc[mt][nt][v4],
                                                orow + nt * 16 + l15);
            }
        }
    }
}

extern "C" void kernel_launch(void* const* d_in, const int* in_sizes, int n_in,
                              void* d_out, int out_size, void* d_ws, size_t ws_size,
                              hipStream_t stream) {
    const float* x  = (const float*)d_in[0];   // (8192, 1728) fp32
    const float* v  = (const float*)d_in[1];   // (3, 64, 49, 256) fp32
    const float* b  = (const float*)d_in[2];   // (12544,) fp32
    float* out = (float*)d_out;                // (8192, 12544) fp32

    unsigned short* wt = (unsigned short*)d_ws;          // 4.8 MB bf16 wt2

    wt_prepass<<<dim3(6, 49), dim3(256), 0, stream>>>(v, wt);
    tic_gemm<<<dim3(8192 / 32), dim3(256), 0, stream>>>(x, wt, b, out);
}